// Round 1
// baseline (432.306 us; speedup 1.0000x reference)
//
#include <hip/hip_runtime.h>

typedef unsigned short ushort_t;
typedef __bf16 bf16x8 __attribute__((ext_vector_type(8)));
typedef float f32x4 __attribute__((ext_vector_type(4)));

#define SCALE_F 0.17677669529663687f  // 32^-0.5

__device__ __forceinline__ ushort_t f2bf(float f) {
  union { float f; unsigned u; } v; v.f = f;
  unsigned u = v.u;
  return (ushort_t)((u + 0x7FFFu + ((u >> 16) & 1u)) >> 16);  // RNE
}

// ---- prologue: transposed bf16 weights into workspace ----
// wqkvT[n][k] = wqkv[k][n]  (768 x 256), woutT[n][k] = wout[k][n] (256 x 256)
__global__ __launch_bounds__(256, 1) void prep_weights(
    const float* __restrict__ wqkv, const float* __restrict__ wout,
    ushort_t* __restrict__ wqkvT, ushort_t* __restrict__ woutT) {
  int i = blockIdx.x * 256 + threadIdx.x;
  if (i < 768 * 256) {
    int n = i >> 8, k = i & 255;
    wqkvT[i] = f2bf(wqkv[k * 768 + n]);
  } else {
    int j = i - 768 * 256;
    int n = j >> 8, k = j & 255;
    woutT[j] = f2bf(wout[k * 256 + n]);
  }
}

// ---- fused shifted-window attention: one workgroup per window ----
// LDS map (bytes):
//   [0,      36864) : Xs bf16 [64][264]  (phase0/1)  -> P per-wave [64][72] (phase2)
//   [36864, 70656)  : Qs bf16 [64][264]              -> Os overlay (phase2/3)
//   [70656, 104448) : Ks bf16 [64][264]
//   [104448,141312) : Vt bf16 [256][72]   (V transposed: Vt[ch][tok])
//   [141312,148512) : pos_enc f32 [8*225]
//   [148512,148768) : lab  i32 [64]
__global__ __launch_bounds__(256, 1) void swin_attn(
    const float* __restrict__ x,
    const float* __restrict__ b_qkv,
    const float* __restrict__ b_out,
    const float* __restrict__ pos_enc,
    const ushort_t* __restrict__ wqkvT,
    const ushort_t* __restrict__ woutT,
    float* __restrict__ out) {
  __shared__ __attribute__((aligned(16))) char smem[148768];
  ushort_t* Xs = (ushort_t*)smem;
  ushort_t* Qs = (ushort_t*)(smem + 36864);
  ushort_t* Ks = (ushort_t*)(smem + 70656);
  ushort_t* Vt = (ushort_t*)(smem + 104448);
  float*    pe = (float*)(smem + 141312);
  int*     lab = (int*)(smem + 148512);

  const int tid  = threadIdx.x;
  const int wid  = blockIdx.x;
  const int bb   = wid >> 6;
  const int w64  = wid & 63;
  const int wy   = w64 >> 3, wx = w64 & 7;
  const int wave = tid >> 6, lane = tid & 63;
  const int g    = lane >> 4, cc = lane & 15;

  // ---------------- phase 0: shifted-window gather -> bf16 LDS ----------------
  {
    const float* xb = x + (size_t)bb * 4096 * 256;
    #pragma unroll
    for (int it = 0; it < 16; ++it) {
      int fi = tid + 256 * it;       // float4 index within the 64x(256/4) tile
      int r = fi >> 6, c4 = fi & 63;
      int hh = (8 * wy + (r >> 3) + 4) & 63;
      int ww = (8 * wx + (r & 7) + 4) & 63;
      const float4 v = ((const float4*)(xb + ((size_t)hh * 64 + ww) * 256))[c4];
      uint2 pk;
      pk.x = (unsigned)f2bf(v.x) | ((unsigned)f2bf(v.y) << 16);
      pk.y = (unsigned)f2bf(v.z) | ((unsigned)f2bf(v.w) << 16);
      *(uint2*)&Xs[r * 264 + 4 * c4] = pk;
    }
    for (int i = tid; i < 1800; i += 256) pe[i] = pos_enc[i];
    if (tid < 64) {
      int py = 8 * wy + (tid >> 3), px = 8 * wx + (tid & 7);
      int ry = (py < 56) ? 0 : (py < 60 ? 1 : 2);
      int rx = (px < 56) ? 0 : (px < 60 ? 1 : 2);
      lab[tid] = ry * 3 + rx;
    }
  }
  __syncthreads();

  // ---------------- phase 1: QKV GEMM (64x256 @ 256x768) ----------------
  {
    bf16x8 af[4][8];  // A fragments cached: all 64 rows x K=256
    #pragma unroll
    for (int mt = 0; mt < 4; ++mt)
      #pragma unroll
      for (int ks = 0; ks < 8; ++ks)
        af[mt][ks] = *(const bf16x8*)&Xs[(16 * mt + cc) * 264 + 32 * ks + 8 * g];

    #pragma unroll 1
    for (int ntl = 0; ntl < 12; ++ntl) {   // each wave owns 192 output cols
      int cn = 192 * wave + 16 * ntl;
      f32x4 acc[4];
      #pragma unroll
      for (int mt = 0; mt < 4; ++mt) acc[mt] = (f32x4){0.f, 0.f, 0.f, 0.f};
      #pragma unroll
      for (int ks = 0; ks < 8; ++ks) {
        bf16x8 bfr = *(const bf16x8*)&wqkvT[(cn + cc) * 256 + 32 * ks + 8 * g];
        #pragma unroll
        for (int mt = 0; mt < 4; ++mt)
          acc[mt] = __builtin_amdgcn_mfma_f32_16x16x32_bf16(af[mt][ks], bfr, acc[mt], 0, 0, 0);
      }
      float bias = b_qkv[cn + cc];
      int sel = cn >> 8, cin = cn & 255;
      #pragma unroll
      for (int mt = 0; mt < 4; ++mt)
        #pragma unroll
        for (int i = 0; i < 4; ++i) {
          int row = 16 * mt + 4 * g + i;  // D: col=lane&15, row=(lane>>4)*4+i
          ushort_t bv = f2bf(acc[mt][i] + bias);
          if (sel == 0)      Qs[row * 264 + cin + cc] = bv;
          else if (sel == 1) Ks[row * 264 + cin + cc] = bv;
          else               Vt[(cin + cc) * 72 + row] = bv;  // store V transposed
        }
    }
  }
  __syncthreads();

  // ---------------- phase 2: attention, 2 heads per wave ----------------
  ushort_t* Pw = Xs + wave * 4608;  // per-wave P [64][72] bf16 (overlays Xs)
  #pragma unroll 1
  for (int hi = 0; hi < 2; ++hi) {
    int h = 2 * wave + hi;
    int koff = 32 * h + 8 * g;
    bf16x8 qf[4], kf[4];
    #pragma unroll
    for (int t = 0; t < 4; ++t) {
      qf[t] = *(const bf16x8*)&Qs[(16 * t + cc) * 264 + koff];
      kf[t] = *(const bf16x8*)&Ks[(16 * t + cc) * 264 + koff];
    }
    f32x4 sacc[4][4];
    #pragma unroll
    for (int mt = 0; mt < 4; ++mt)
      #pragma unroll
      for (int nt = 0; nt < 4; ++nt)
        sacc[mt][nt] = (f32x4){0.f, 0.f, 0.f, 0.f};
    #pragma unroll
    for (int nt = 0; nt < 4; ++nt)
      #pragma unroll
      for (int mt = 0; mt < 4; ++mt)
        sacc[mt][nt] = __builtin_amdgcn_mfma_f32_16x16x32_bf16(qf[mt], kf[nt], sacc[mt][nt], 0, 0, 0);

    // scale + rel-pos bias + shift mask + row softmax (rows live in 16-lane groups)
    const float* peh = pe + h * 225;
    #pragma unroll
    for (int mt = 0; mt < 4; ++mt) {
      #pragma unroll
      for (int i = 0; i < 4; ++i) {
        int q = 16 * mt + 4 * g + i;
        int y1 = q >> 3, x1 = q & 7;
        int lq = lab[q];
        float sv[4];
        #pragma unroll
        for (int nt = 0; nt < 4; ++nt) {
          int kk = 16 * nt + cc;
          float bias = peh[(y1 - (kk >> 3) + 7) * 15 + (x1 - (kk & 7) + 7)];
          float s = sacc[mt][nt][i] * SCALE_F + bias;
          sv[nt] = (lq != lab[kk]) ? -1e30f : s;
        }
        float m = fmaxf(fmaxf(sv[0], sv[1]), fmaxf(sv[2], sv[3]));
        m = fmaxf(m, __shfl_xor(m, 1));
        m = fmaxf(m, __shfl_xor(m, 2));
        m = fmaxf(m, __shfl_xor(m, 4));
        m = fmaxf(m, __shfl_xor(m, 8));
        float p0 = __expf(sv[0] - m), p1 = __expf(sv[1] - m);
        float p2 = __expf(sv[2] - m), p3 = __expf(sv[3] - m);
        float sum = p0 + p1 + p2 + p3;
        sum += __shfl_xor(sum, 1);
        sum += __shfl_xor(sum, 2);
        sum += __shfl_xor(sum, 4);
        sum += __shfl_xor(sum, 8);
        float rinv = 1.0f / sum;
        int ro = q * 72;
        Pw[ro + 0  + cc] = f2bf(p0 * rinv);
        Pw[ro + 16 + cc] = f2bf(p1 * rinv);
        Pw[ro + 32 + cc] = f2bf(p2 * rinv);
        Pw[ro + 48 + cc] = f2bf(p3 * rinv);
      }
    }
    asm volatile("s_waitcnt lgkmcnt(0)" ::: "memory");

    // O = P @ V  (K=64 over keys), V consumed from transposed LDS
    bf16x8 pf[4][2], vf[2][2];
    #pragma unroll
    for (int mt = 0; mt < 4; ++mt)
      #pragma unroll
      for (int ks = 0; ks < 2; ++ks)
        pf[mt][ks] = *(const bf16x8*)&Pw[(16 * mt + cc) * 72 + 32 * ks + 8 * g];
    #pragma unroll
    for (int nt = 0; nt < 2; ++nt)
      #pragma unroll
      for (int ks = 0; ks < 2; ++ks)
        vf[nt][ks] = *(const bf16x8*)&Vt[(32 * h + 16 * nt + cc) * 72 + 32 * ks + 8 * g];
    f32x4 oacc[4][2];
    #pragma unroll
    for (int mt = 0; mt < 4; ++mt)
      #pragma unroll
      for (int nt = 0; nt < 2; ++nt)
        oacc[mt][nt] = (f32x4){0.f, 0.f, 0.f, 0.f};
    #pragma unroll
    for (int ks = 0; ks < 2; ++ks)
      #pragma unroll
      for (int nt = 0; nt < 2; ++nt)
        #pragma unroll
        for (int mt = 0; mt < 4; ++mt)
          oacc[mt][nt] = __builtin_amdgcn_mfma_f32_16x16x32_bf16(pf[mt][ks], vf[nt][ks], oacc[mt][nt], 0, 0, 0);

    // store O into Qs overlay: this wave's own head columns only -> race-free
    #pragma unroll
    for (int mt = 0; mt < 4; ++mt)
      #pragma unroll
      for (int nt = 0; nt < 2; ++nt)
        #pragma unroll
        for (int i = 0; i < 4; ++i)
          Qs[(16 * mt + 4 * g + i) * 264 + 32 * h + 16 * nt + cc] = f2bf(oacc[mt][nt][i]);
  }
  __syncthreads();

  // ---------------- phase 3: out projection + reverse-shift scatter ----------------
  {
    bf16x8 af[4][8];
    #pragma unroll
    for (int mt = 0; mt < 4; ++mt)
      #pragma unroll
      for (int ks = 0; ks < 8; ++ks)
        af[mt][ks] = *(const bf16x8*)&Qs[(16 * mt + cc) * 264 + 32 * ks + 8 * g];
    #pragma unroll 1
    for (int nt = 0; nt < 4; ++nt) {       // each wave owns 64 output channels
      int cs = 64 * wave + 16 * nt;
      f32x4 pa[4];
      #pragma unroll
      for (int mt = 0; mt < 4; ++mt) pa[mt] = (f32x4){0.f, 0.f, 0.f, 0.f};
      #pragma unroll
      for (int ks = 0; ks < 8; ++ks) {
        bf16x8 bfr = *(const bf16x8*)&woutT[(cs + cc) * 256 + 32 * ks + 8 * g];
        #pragma unroll
        for (int mt = 0; mt < 4; ++mt)
          pa[mt] = __builtin_amdgcn_mfma_f32_16x16x32_bf16(af[mt][ks], bfr, pa[mt], 0, 0, 0);
      }
      float bo = b_out[cs + cc];
      #pragma unroll
      for (int mt = 0; mt < 4; ++mt)
        #pragma unroll
        for (int i = 0; i < 4; ++i) {
          int q = 16 * mt + 4 * g + i;
          int hh = (8 * wy + (q >> 3) + 4) & 63;
          int ww = (8 * wx + (q & 7) + 4) & 63;
          out[(((size_t)bb * 4096) + hh * 64 + ww) * 256 + cs + cc] = pa[mt][i] + bo;
        }
    }
  }
}

extern "C" void kernel_launch(void* const* d_in, const int* in_sizes, int n_in,
                              void* d_out, int out_size, void* d_ws, size_t ws_size,
                              hipStream_t stream) {
  const float* x       = (const float*)d_in[0];
  const float* w_qkv   = (const float*)d_in[1];
  const float* b_qkv   = (const float*)d_in[2];
  const float* w_out   = (const float*)d_in[3];
  const float* b_out   = (const float*)d_in[4];
  const float* pos_enc = (const float*)d_in[5];
  float* out = (float*)d_out;

  ushort_t* wqkvT = (ushort_t*)d_ws;            // 768*256 bf16
  ushort_t* woutT = wqkvT + 768 * 256;          // 256*256 bf16  (total 512 KB)

  prep_weights<<<dim3((768 * 256 + 256 * 256) / 256), dim3(256), 0, stream>>>(
      w_qkv, w_out, wqkvT, woutT);
  swin_attn<<<dim3(2048), dim3(256), 0, stream>>>(
      x, b_qkv, b_out, pos_enc, wqkvT, woutT, out);
}